// Round 13
// baseline (1663.484 us; speedup 1.0000x reference)
//
#include <hip/hip_runtime.h>

#define NN 8192
#define DD 64
#define CC 128       // 2*DD
#define PANEL_W 4096 // f32 score panel: 8192*4096*4B = 128MB inside d_out

// ---- d_out scratch layout (f32 element offsets; total 67,108,864 floats) --
#define OFF_W32  33554432u   // 8192*128 f32 nodevecs (rows 4096-4223)
#define OFF_CVAL 36700160u   // 8192*128 f32 screen candidates (2 panels x 64)
#define OFF_CIDX 37748736u   // 8192*128 i32
#define OFF_MIDX 66060288u   // 8192*64  i32 merged ranked top-64 (rows 8064-8127)
#define OFF_MVAL 66584576u   // 8192*64  f32 merged scores        (rows 8128-8191)
#define TAILROW0 8064        // rows >= here written only by k4c (single block)

// Optimization barrier: forces v into a VGPR and blocks FMA contraction
// across it (hipcc default -ffp-contract=fast would otherwise fuse
// fl(0.01*nz) into the following add -> 1-ulp score changes -> topk flips).
__device__ __forceinline__ float guard(float v) {
    asm volatile("" : "+v"(v));
    return v;
}

// ---- EXACT replica of XLA EmitFastTanh f32, with_fma = true ---------------
// xla/service/llvm_ir/math_ops.cc: clamp to +-7.99881172180175781 (the
// WITH_FMA clamp; no-fma uses 7.90531110763549805), |x| < 0.0004 -> x,
// Eigen deg-13/6 rational, Horner with FMA.
__device__ __forceinline__ float xla_tanhf(float x) {
    float xc = fminf(fmaxf(x, -7.99881172180175781f), 7.99881172180175781f);
    float x2 = xc * xc;
    float p = fmaf(x2, -2.76076847742355e-16f, 2.00018790482477e-13f);
    p = fmaf(x2, p, -8.60467152213735e-11f);
    p = fmaf(x2, p, 5.12229709037114e-08f);
    p = fmaf(x2, p, 1.48572235717979e-05f);
    p = fmaf(x2, p, 6.37261928875436e-04f);
    p = fmaf(x2, p, 4.89352455891786e-03f);
    p = xc * p;
    float q = fmaf(x2, 1.19825839466702e-06f, 1.18534705686654e-04f);
    q = fmaf(x2, q, 2.26843463243900e-03f);
    q = fmaf(x2, q, 4.89352518554385e-03f);
    float r = p / q;
    return (fabsf(x) < 0.0004f) ? x : r;
}

// score = relu(tanh(3a)) + 0.01*noise with XLA's op-level rounding:
// adj = max(tanh(fl(3a)), 0); score = fl(adj + fl(0.01*nz)); NO contraction.
__device__ __forceinline__ float score_of(float a, float nz) {
    float adj = fmaxf(xla_tanhf(3.0f * a), 0.0f);
    float m = guard(0.01f * nz);
    return adj + m;
}

// ---------------------------------------------------------------- K1
// nodevec = xla_tanhf(3*(emb[idx]@W^T + b)), f32 ascending-k fma dot
// (bitwise = Eigen gebp: one accumulator per output, sequential k, FMA).
__global__ __launch_bounds__(256) void k1_nodevec(
    const int* __restrict__ idx,
    const float* __restrict__ emb1, const float* __restrict__ emb2,
    const float* __restrict__ w1, const float* __restrict__ b1,
    const float* __restrict__ w2, const float* __restrict__ b2,
    float* __restrict__ W32)
{
    __shared__ float sw1[64 * 65], sw2[64 * 65];
    __shared__ float sb1[64], sb2[64];
    __shared__ float se1[4][64], se2[4][64];
    int t = threadIdx.x;
    for (int i = t; i < 4096; i += 256) {
        int r = i >> 6, c = i & 63;
        sw1[r * 65 + c] = w1[i];
        sw2[r * 65 + c] = w2[i];
    }
    if (t < 64) { sb1[t] = b1[t]; sb2[t] = b2[t]; }
    int nl = t >> 6, d = t & 63;
    int n = blockIdx.x * 4 + nl;
    bool is64 = (idx[1] == 0);            // arange: int32 -> 1, int64 LE -> 0
    int g = (is64 ? idx[2 * n] : idx[n]) & 8191;
    se1[nl][d] = emb1[g * 64 + d];
    se2[nl][d] = emb2[g * 64 + d];
    __syncthreads();
    float z1 = 0.0f, z2 = 0.0f;
#pragma unroll 16
    for (int q = 0; q < 64; ++q) {
        z1 = fmaf(se1[nl][q], sw1[d * 65 + q], z1);
        z2 = fmaf(se2[nl][q], sw2[d * 65 + q], z2);
    }
    z1 = 3.0f * guard(z1 + sb1[d]);       // add THEN mul: no fma shape
    z2 = 3.0f * guard(z2 + sb2[d]);
    W32[n * CC + d]      = xla_tanhf(z1);
    W32[n * CC + 64 + d] = xla_tanhf(z2);
}

// ---------------------------------------------------------------- K2
// Panel scores with a = fl(s1) - fl(s2); s1 = nv1_i.nv2_j, s2 = nv2_i.nv1_j
// accumulated SEPARATELY, ascending k, f32 FMA (two matmuls like the ref).
__global__ __launch_bounds__(256) void k2_score(
    const float* __restrict__ Wv, const float* __restrict__ noise,
    float* __restrict__ Sp, int colOff)
{
    __shared__ float sA[32 * 128];
    __shared__ float sB[32 * 128];
    int t  = threadIdx.x;
    int row0 = blockIdx.y * 128;
    int col0 = blockIdx.x * 128;
    int ty = t >> 4, tx = t & 15;

    float acc1[8][8], acc2[8][8];
#pragma unroll
    for (int i = 0; i < 8; ++i)
#pragma unroll
        for (int j = 0; j < 8; ++j) { acc1[i][j] = 0.0f; acc2[i][j] = 0.0f; }

    for (int kc = 0; kc < 4; ++kc) {
        int k0 = kc * 32;        // A cols: 0-63 = nv1_i, 64-127 = nv2_i
        int kB = k0 ^ 64;        // B swapped half: nv2_j then nv1_j
#pragma unroll
        for (int p = 0; p < 4; ++p) {
            int q = p * 256 + t;
            int r = q >> 3;
            int f = q & 7;
            float4 av = *(const float4*)&Wv[(row0 + r) * CC + k0 + f * 4];
            float4 bv = *(const float4*)&Wv[(colOff + col0 + r) * CC + kB + f * 4];
            int kk = f * 4;
            sA[(kk + 0) * 128 + r] = av.x;
            sA[(kk + 1) * 128 + r] = av.y;
            sA[(kk + 2) * 128 + r] = av.z;
            sA[(kk + 3) * 128 + r] = av.w;
            sB[(kk + 0) * 128 + r] = bv.x;
            sB[(kk + 1) * 128 + r] = bv.y;
            sB[(kk + 2) * 128 + r] = bv.z;
            sB[(kk + 3) * 128 + r] = bv.w;
        }
        __syncthreads();
        bool first = (kc < 2);
#pragma unroll 8
        for (int kk = 0; kk < 32; ++kk) {
            float4 a0 = *(const float4*)&sA[kk * 128 + ty * 8];
            float4 a1 = *(const float4*)&sA[kk * 128 + ty * 8 + 4];
            float4 b0 = *(const float4*)&sB[kk * 128 + tx * 8];
            float4 b1 = *(const float4*)&sB[kk * 128 + tx * 8 + 4];
            float a[8] = {a0.x, a0.y, a0.z, a0.w, a1.x, a1.y, a1.z, a1.w};
            float b[8] = {b0.x, b0.y, b0.z, b0.w, b1.x, b1.y, b1.z, b1.w};
            if (first) {
#pragma unroll
                for (int i = 0; i < 8; ++i)
#pragma unroll
                    for (int j = 0; j < 8; ++j)
                        acc1[i][j] = fmaf(a[i], b[j], acc1[i][j]);
            } else {
#pragma unroll
                for (int i = 0; i < 8; ++i)
#pragma unroll
                    for (int j = 0; j < 8; ++j)
                        acc2[i][j] = fmaf(a[i], b[j], acc2[i][j]);
            }
        }
        __syncthreads();
    }
#pragma unroll
    for (int i = 0; i < 8; ++i) {
        int gr = row0 + ty * 8 + i;
#pragma unroll
        for (int j = 0; j < 8; j += 4) {
            int gc = col0 + tx * 8 + j;
            float4 nz = *(const float4*)&noise[(size_t)gr * NN + colOff + gc];
            float4 o;
            o.x = score_of(guard(acc1[i][j + 0] - acc2[i][j + 0]), nz.x);
            o.y = score_of(guard(acc1[i][j + 1] - acc2[i][j + 1]), nz.y);
            o.z = score_of(guard(acc1[i][j + 2] - acc2[i][j + 2]), nz.z);
            o.w = score_of(guard(acc1[i][j + 3] - acc2[i][j + 3]), nz.w);
            *(float4*)&Sp[(size_t)gr * PANEL_W + gc] = o;
        }
    }
}

// ---------------------------------------------------------------- KS
// Brute-force exact stable top-64 of one panel row (64 argmax passes over
// an LDS-resident row). Ties: lowest index (= lax.top_k stable).
__global__ __launch_bounds__(256) void kS_sel(
    const float* __restrict__ Sp, float* __restrict__ candVal,
    int* __restrict__ candIdx, int colOff, int slot0)
{
    __shared__ float sv[PANEL_W];
    __shared__ float rv[4];
    __shared__ int   ri[4];
    int t = threadIdx.x;
    int row = blockIdx.x;
    const float* Srow = Sp + (size_t)row * PANEL_W;
    for (int i = t; i < PANEL_W / 4; i += 256)
        *(float4*)&sv[i * 4] = *(const float4*)&Srow[i * 4];
    __syncthreads();
    int lane = t & 63, w = t >> 6;
    for (int r = 0; r < 64; ++r) {
        float bv = -1.0f; int bi = PANEL_W - 1;
        int base = t * 16;
#pragma unroll
        for (int e = 0; e < 16; ++e) {
            float v = sv[base + e];
            if (v > bv) { bv = v; bi = base + e; }   // strict > keeps lowest idx
        }
        for (int off = 32; off; off >>= 1) {
            float ov = __shfl_down(bv, off);
            int   oi = __shfl_down(bi, off);
            if (ov > bv || (ov == bv && oi < bi)) { bv = ov; bi = oi; }
        }
        if (lane == 0) { rv[w] = bv; ri[w] = bi; }
        __syncthreads();
        if (t == 0) {
            float Bv = rv[0]; int Bi = ri[0];
            for (int q = 1; q < 4; ++q)
                if (rv[q] > Bv || (rv[q] == Bv && ri[q] < Bi)) { Bv = rv[q]; Bi = ri[q]; }
            candVal[row * 128 + slot0 + r] = Bv;
            candIdx[row * 128 + slot0 + r] = colOff + Bi;
            sv[Bi] = -2.0f;                          // below all real scores
        }
        __syncthreads();
    }
}

// ---------------------------------------------------------------- K_MERGE
// Stable rank of the 128 screen candidates; keep ranked top-64 (idx+score).
__global__ __launch_bounds__(128) void k_merge(
    const float* __restrict__ candVal, const int* __restrict__ candIdx,
    int* __restrict__ mrgIdx, float* __restrict__ mrgVal)
{
    __shared__ float mv[128];
    __shared__ int   mi[128];
    int t = threadIdx.x, row = blockIdx.x;
    mv[t] = candVal[row * 128 + t];
    mi[t] = candIdx[row * 128 + t];
    __syncthreads();
    float v = mv[t]; int i0 = mi[t];
    int rank = 0;
    for (int s = 0; s < 128; ++s) {
        float vs = mv[s]; int is = mi[s];
        if (s != t && (vs > v || (vs == v && is < i0))) ++rank;
    }
    if (rank < 64) {
        mrgIdx[row * 64 + rank] = i0;
        mrgVal[row * 64 + rank] = v;
    }
}

// ---------------------------------------------------------------- K4a
// Zero + unit diagonal for rows [0, TAILROW0).
__global__ __launch_bounds__(256) void k4a_fill(float* __restrict__ out)
{
    int i4 = blockIdx.x * 256 + threadIdx.x;   // float4 index < 16,515,072
    int f0 = i4 * 4;
    int row = f0 >> 13;
    int colbase = f0 & 8191;
    int drel = row - colbase;
    float4 z = make_float4(0.f, 0.f, 0.f, 0.f);
    if (drel >= 0 && drel < 4) ((float*)&z)[drel] = 1.0f;
    *(float4*)&out[f0] = z;
}

// ---------------------------------------------------------------- K4b
// Scatter top-k adj = fl(score - fl(0.01*nz)) for rows [0, TAILROW0).
// (<=1ulp value error vs golden adj; threshold 2e-2; selection is exact.)
__global__ __launch_bounds__(256) void k4b_scatter(
    const int* __restrict__ mrgIdx, const float* __restrict__ mrgVal,
    const float* __restrict__ noise, const int* __restrict__ kptr,
    float* __restrict__ out)
{
    int lane = threadIdx.x & 63;
    int w    = threadIdx.x >> 6;
    int row  = blockIdx.x * 4 + w;
    int kk = kptr[0]; if (kk > 64) kk = 64; if (kk < 1) kk = 1;
    if (lane < kk) {
        int   j = mrgIdx[row * 64 + lane] & 8191;
        float s = mrgVal[row * 64 + lane];
        float nz = noise[(size_t)row * NN + j];
        float m = guard(0.01f * nz);
        float adj = s - m;
        if (j == row) adj += 1.0f;
        out[(size_t)row * NN + j] = adj;
    }
}

// ---------------------------------------------------------------- K4c
// SINGLE BLOCK: rows [TAILROW0, 8192) whose bytes hold mrgIdx/mrgVal.
__global__ __launch_bounds__(1024) void k4c_tail(
    const int* __restrict__ mrgIdx, const float* __restrict__ mrgVal,
    const float* __restrict__ noise, const int* __restrict__ kptr,
    float* __restrict__ out)
{
    __shared__ int   sIdx[128 * 64];
    __shared__ float sVal[128 * 64];
    int t = threadIdx.x;
    int kk = kptr[0]; if (kk > 64) kk = 64; if (kk < 1) kk = 1;

    for (int i = t; i < 128 * 64; i += 1024) {
        sIdx[i] = mrgIdx[(TAILROW0 + (i >> 6)) * 64 + (i & 63)];
        sVal[i] = mrgVal[(TAILROW0 + (i >> 6)) * 64 + (i & 63)];
    }
    __syncthreads();

    const int base = TAILROW0 * NN;           // 66,060,288 fits int
    for (int q = t; q < 262144; q += 1024) {  // float4 count for 128 rows
        int f0 = base + q * 4;
        int row = f0 >> 13;
        int colbase = f0 & 8191;
        int drel = row - colbase;
        float4 z = make_float4(0.f, 0.f, 0.f, 0.f);
        if (drel >= 0 && drel < 4) ((float*)&z)[drel] = 1.0f;
        *(float4*)&out[f0] = z;
    }
    __syncthreads();

    for (int i = t; i < 128 * 64; i += 1024) {
        int s = i & 63;
        if (s < kk) {
            int row = TAILROW0 + (i >> 6);
            int j = sIdx[i] & 8191;
            float nz = noise[(size_t)row * NN + j];
            float m = guard(0.01f * nz);
            float adj = sVal[i] - m;
            if (j == row) adj += 1.0f;
            out[(size_t)row * NN + j] = adj;
        }
    }
}

extern "C" void kernel_launch(void* const* d_in, const int* in_sizes, int n_in,
                              void* d_out, int out_size, void* d_ws, size_t ws_size,
                              hipStream_t stream) {
    (void)in_sizes; (void)n_in; (void)out_size; (void)d_ws; (void)ws_size;
    const int*   idx   = (const int*)d_in[0];
    const float* emb1  = (const float*)d_in[1];
    const float* emb2  = (const float*)d_in[2];
    const float* w1    = (const float*)d_in[3];
    const float* b1    = (const float*)d_in[4];
    const float* w2    = (const float*)d_in[5];
    const float* b2    = (const float*)d_in[6];
    const float* noise = (const float*)d_in[7];
    const int*   kptr  = (const int*)d_in[8];

    float* out = (float*)d_out;
    float* Sp      = out;                    // panel (transient)
    float* W32     = out + OFF_W32;
    float* candVal = out + OFF_CVAL;
    int*   candIdx = (int*)(out + OFF_CIDX);
    int*   mrgIdx  = (int*)(out + OFF_MIDX);
    float* mrgVal  = out + OFF_MVAL;

    k1_nodevec<<<NN / 4, 256, 0, stream>>>(idx, emb1, emb2, w1, b1, w2, b2, W32);

    dim3 g2(PANEL_W / 128, NN / 128);
    for (int p = 0; p < 2; ++p) {
        int colOff = p * PANEL_W;
        k2_score<<<g2, 256, 0, stream>>>(W32, noise, Sp, colOff);
        kS_sel<<<NN, 256, 0, stream>>>(Sp, candVal, candIdx, colOff, p * 64);
    }
    k_merge<<<NN, 128, 0, stream>>>(candVal, candIdx, mrgIdx, mrgVal);

    k4a_fill<<<64512, 256, 0, stream>>>(out);                       // rows [0,8064)
    k4b_scatter<<<TAILROW0 / 4, 256, 0, stream>>>(mrgIdx, mrgVal, noise, kptr, out);
    k4c_tail<<<1, 1024, 0, stream>>>(mrgIdx, mrgVal, noise, kptr, out);
}

// Round 14
// 687.734 us; speedup vs baseline: 2.4188x; 2.4188x over previous
//
#include <hip/hip_runtime.h>

#define NN 8192
#define DD 64
#define CC 128       // 2*DD
#define PANEL_W 4096 // f32 score panel: 8192*4096*4B = 128MB inside d_out

// ---- d_out scratch layout (f32 element offsets; total 67,108,864 floats) --
#define OFF_W32  33554432u   // 8192*128 f32 nodevecs (rows 4096-4223)
#define OFF_MIDX 66060288u   // 8192*64  i32 ranked top-64 list (rows 8064-8127)
#define OFF_MVAL 66584576u   // 8192*64  f32 list scores        (rows 8128-8191)
#define TAILROW0 8064        // rows >= here written only by k4c (single block)

// Optimization barrier: blocks FMA contraction across it (hipcc default
// -ffp-contract=fast would fuse fl(0.01*nz) into the add -> topk flips).
__device__ __forceinline__ float guard(float v) {
    asm volatile("" : "+v"(v));
    return v;
}

// ---- EXACT replica of XLA EmitFastTanh f32, with_fma = true (VERIFIED) ----
__device__ __forceinline__ float xla_tanhf(float x) {
    float xc = fminf(fmaxf(x, -7.99881172180175781f), 7.99881172180175781f);
    float x2 = xc * xc;
    float p = fmaf(x2, -2.76076847742355e-16f, 2.00018790482477e-13f);
    p = fmaf(x2, p, -8.60467152213735e-11f);
    p = fmaf(x2, p, 5.12229709037114e-08f);
    p = fmaf(x2, p, 1.48572235717979e-05f);
    p = fmaf(x2, p, 6.37261928875436e-04f);
    p = fmaf(x2, p, 4.89352455891786e-03f);
    p = xc * p;
    float q = fmaf(x2, 1.19825839466702e-06f, 1.18534705686654e-04f);
    q = fmaf(x2, q, 2.26843463243900e-03f);
    q = fmaf(x2, q, 4.89352518554385e-03f);
    float r = p / q;
    return (fabsf(x) < 0.0004f) ? x : r;
}

// score = fl(max(tanh(fl(3a)),0) + fl(0.01*nz)), no contraction (VERIFIED)
__device__ __forceinline__ float score_of(float a, float nz) {
    float adj = fmaxf(xla_tanhf(3.0f * a), 0.0f);
    float m = guard(0.01f * nz);
    return adj + m;
}

// ---------------------------------------------------------------- K1 (VERIFIED)
__global__ __launch_bounds__(256) void k1_nodevec(
    const int* __restrict__ idx,
    const float* __restrict__ emb1, const float* __restrict__ emb2,
    const float* __restrict__ w1, const float* __restrict__ b1,
    const float* __restrict__ w2, const float* __restrict__ b2,
    float* __restrict__ W32)
{
    __shared__ float sw1[64 * 65], sw2[64 * 65];
    __shared__ float sb1[64], sb2[64];
    __shared__ float se1[4][64], se2[4][64];
    int t = threadIdx.x;
    for (int i = t; i < 4096; i += 256) {
        int r = i >> 6, c = i & 63;
        sw1[r * 65 + c] = w1[i];
        sw2[r * 65 + c] = w2[i];
    }
    if (t < 64) { sb1[t] = b1[t]; sb2[t] = b2[t]; }
    int nl = t >> 6, d = t & 63;
    int n = blockIdx.x * 4 + nl;
    bool is64 = (idx[1] == 0);            // arange: int32 -> 1, int64 LE -> 0
    int g = (is64 ? idx[2 * n] : idx[n]) & 8191;
    se1[nl][d] = emb1[g * 64 + d];
    se2[nl][d] = emb2[g * 64 + d];
    __syncthreads();
    float z1 = 0.0f, z2 = 0.0f;
#pragma unroll 16
    for (int q = 0; q < 64; ++q) {
        z1 = fmaf(se1[nl][q], sw1[d * 65 + q], z1);
        z2 = fmaf(se2[nl][q], sw2[d * 65 + q], z2);
    }
    z1 = 3.0f * guard(z1 + sb1[d]);
    z2 = 3.0f * guard(z2 + sb2[d]);
    W32[n * CC + d]      = xla_tanhf(z1);
    W32[n * CC + 64 + d] = xla_tanhf(z2);
}

// ---------------------------------------------------------------- K_INIT
__global__ __launch_bounds__(256) void k_init(
    float* __restrict__ listVal, int* __restrict__ listIdx)
{
    int i = blockIdx.x * 256 + threadIdx.x;   // NN*64 entries
    listVal[i] = -1.0f;
    listIdx[i] = -1;
}

// ---------------------------------------------------------------- K2 (VERIFIED)
__global__ __launch_bounds__(256) void k2_score(
    const float* __restrict__ Wv, const float* __restrict__ noise,
    float* __restrict__ Sp, int colOff)
{
    __shared__ float sA[32 * 128];
    __shared__ float sB[32 * 128];
    int t  = threadIdx.x;
    int row0 = blockIdx.y * 128;
    int col0 = blockIdx.x * 128;
    int ty = t >> 4, tx = t & 15;

    float acc1[8][8], acc2[8][8];
#pragma unroll
    for (int i = 0; i < 8; ++i)
#pragma unroll
        for (int j = 0; j < 8; ++j) { acc1[i][j] = 0.0f; acc2[i][j] = 0.0f; }

    for (int kc = 0; kc < 4; ++kc) {
        int k0 = kc * 32;        // A cols: 0-63 = nv1_i, 64-127 = nv2_i
        int kB = k0 ^ 64;        // B swapped half: nv2_j then nv1_j
#pragma unroll
        for (int p = 0; p < 4; ++p) {
            int q = p * 256 + t;
            int r = q >> 3;
            int f = q & 7;
            float4 av = *(const float4*)&Wv[(row0 + r) * CC + k0 + f * 4];
            float4 bv = *(const float4*)&Wv[(colOff + col0 + r) * CC + kB + f * 4];
            int kk = f * 4;
            sA[(kk + 0) * 128 + r] = av.x;
            sA[(kk + 1) * 128 + r] = av.y;
            sA[(kk + 2) * 128 + r] = av.z;
            sA[(kk + 3) * 128 + r] = av.w;
            sB[(kk + 0) * 128 + r] = bv.x;
            sB[(kk + 1) * 128 + r] = bv.y;
            sB[(kk + 2) * 128 + r] = bv.z;
            sB[(kk + 3) * 128 + r] = bv.w;
        }
        __syncthreads();
        bool first = (kc < 2);
#pragma unroll 8
        for (int kk = 0; kk < 32; ++kk) {
            float4 a0 = *(const float4*)&sA[kk * 128 + ty * 8];
            float4 a1 = *(const float4*)&sA[kk * 128 + ty * 8 + 4];
            float4 b0 = *(const float4*)&sB[kk * 128 + tx * 8];
            float4 b1 = *(const float4*)&sB[kk * 128 + tx * 8 + 4];
            float a[8] = {a0.x, a0.y, a0.z, a0.w, a1.x, a1.y, a1.z, a1.w};
            float b[8] = {b0.x, b0.y, b0.z, b0.w, b1.x, b1.y, b1.z, b1.w};
            if (first) {
#pragma unroll
                for (int i = 0; i < 8; ++i)
#pragma unroll
                    for (int j = 0; j < 8; ++j)
                        acc1[i][j] = fmaf(a[i], b[j], acc1[i][j]);
            } else {
#pragma unroll
                for (int i = 0; i < 8; ++i)
#pragma unroll
                    for (int j = 0; j < 8; ++j)
                        acc2[i][j] = fmaf(a[i], b[j], acc2[i][j]);
            }
        }
        __syncthreads();
    }
#pragma unroll
    for (int i = 0; i < 8; ++i) {
        int gr = row0 + ty * 8 + i;
#pragma unroll
        for (int j = 0; j < 8; j += 4) {
            int gc = col0 + tx * 8 + j;
            float4 nz = *(const float4*)&noise[(size_t)gr * NN + colOff + gc];
            float4 o;
            o.x = score_of(guard(acc1[i][j + 0] - acc2[i][j + 0]), nz.x);
            o.y = score_of(guard(acc1[i][j + 1] - acc2[i][j + 1]), nz.y);
            o.z = score_of(guard(acc1[i][j + 2] - acc2[i][j + 2]), nz.z);
            o.w = score_of(guard(acc1[i][j + 3] - acc2[i][j + 3]), nz.w);
            *(float4*)&Sp[(size_t)gr * PANEL_W + gc] = o;
        }
    }
}

// ---------------------------------------------------------------- K3 (NEW)
// One wave per row: persistent sorted top-64 register list, ballot-batched
// insertion. List descending across lanes; candidates processed in
// ascending j; '>' filter + 'Lv >= v stays ahead' = lax.top_k stable
// (lowest index wins ties). Exact f32 top-64 across both panels.
__global__ __launch_bounds__(256) void k3_screen(
    const float* __restrict__ Sp,
    float* __restrict__ listVal, int* __restrict__ listIdx, int colOff)
{
    int lane = threadIdx.x & 63;
    int w    = threadIdx.x >> 6;
    int row  = blockIdx.x * 4 + w;
    const float* Srow = Sp + (size_t)row * PANEL_W;

    float Lv = listVal[row * 64 + lane];
    int   Lj = listIdx[row * 64 + lane];

    for (int c0 = 0; c0 < PANEL_W; c0 += 256) {
        float s0 = Srow[c0 + lane];
        float s1 = Srow[c0 + 64 + lane];
        float s2 = Srow[c0 + 128 + lane];
        float s3 = Srow[c0 + 192 + lane];
#pragma unroll
        for (int u = 0; u < 4; ++u) {
            float s = (u == 0) ? s0 : (u == 1) ? s1 : (u == 2) ? s2 : s3;
            int jb = colOff + c0 + u * 64;
            float tau = __shfl(Lv, 63);
            unsigned long long m = __ballot(s > tau);
            while (m) {
                int b = __ffsll((unsigned long long)m) - 1;
                m &= m - 1;
                float v = __shfl(s, b);
                tau = __shfl(Lv, 63);            // refresh (list grew)
                if (v > tau) {
                    float Lu = __shfl_up(Lv, 1);
                    int   Ju = __shfl_up(Lj, 1);
                    bool ge  = (Lv >= v);                 // ties: earlier j stays
                    bool geu = (lane == 0) || (Lu >= v);
                    float nv = ge ? Lv : (geu ? v : Lu);
                    int   nj = ge ? Lj : (geu ? (jb + b) : Ju);
                    Lv = nv; Lj = nj;
                }
            }
        }
    }
    listVal[row * 64 + lane] = Lv;
    listIdx[row * 64 + lane] = Lj;
}

// ---------------------------------------------------------------- K4a (VERIFIED)
__global__ __launch_bounds__(256) void k4a_fill(float* __restrict__ out)
{
    int i4 = blockIdx.x * 256 + threadIdx.x;   // float4 index < 16,515,072
    int f0 = i4 * 4;
    int row = f0 >> 13;
    int colbase = f0 & 8191;
    int drel = row - colbase;
    float4 z = make_float4(0.f, 0.f, 0.f, 0.f);
    if (drel >= 0 && drel < 4) ((float*)&z)[drel] = 1.0f;
    *(float4*)&out[f0] = z;
}

// ---------------------------------------------------------------- K4b (VERIFIED)
__global__ __launch_bounds__(256) void k4b_scatter(
    const int* __restrict__ mrgIdx, const float* __restrict__ mrgVal,
    const float* __restrict__ noise, const int* __restrict__ kptr,
    float* __restrict__ out)
{
    int lane = threadIdx.x & 63;
    int w    = threadIdx.x >> 6;
    int row  = blockIdx.x * 4 + w;
    int kk = kptr[0]; if (kk > 64) kk = 64; if (kk < 1) kk = 1;
    if (lane < kk) {
        int   j = mrgIdx[row * 64 + lane] & 8191;
        float s = mrgVal[row * 64 + lane];
        float nz = noise[(size_t)row * NN + j];
        float m = guard(0.01f * nz);
        float adj = s - m;
        if (j == row) adj += 1.0f;
        out[(size_t)row * NN + j] = adj;
    }
}

// ---------------------------------------------------------------- K4c (VERIFIED)
__global__ __launch_bounds__(1024) void k4c_tail(
    const int* __restrict__ mrgIdx, const float* __restrict__ mrgVal,
    const float* __restrict__ noise, const int* __restrict__ kptr,
    float* __restrict__ out)
{
    __shared__ int   sIdx[128 * 64];
    __shared__ float sVal[128 * 64];
    int t = threadIdx.x;
    int kk = kptr[0]; if (kk > 64) kk = 64; if (kk < 1) kk = 1;

    for (int i = t; i < 128 * 64; i += 1024) {
        sIdx[i] = mrgIdx[(TAILROW0 + (i >> 6)) * 64 + (i & 63)];
        sVal[i] = mrgVal[(TAILROW0 + (i >> 6)) * 64 + (i & 63)];
    }
    __syncthreads();

    const int base = TAILROW0 * NN;           // 66,060,288 fits int
    for (int q = t; q < 262144; q += 1024) {  // float4 count for 128 rows
        int f0 = base + q * 4;
        int row = f0 >> 13;
        int colbase = f0 & 8191;
        int drel = row - colbase;
        float4 z = make_float4(0.f, 0.f, 0.f, 0.f);
        if (drel >= 0 && drel < 4) ((float*)&z)[drel] = 1.0f;
        *(float4*)&out[f0] = z;
    }
    __syncthreads();

    for (int i = t; i < 128 * 64; i += 1024) {
        int s = i & 63;
        if (s < kk) {
            int row = TAILROW0 + (i >> 6);
            int j = sIdx[i] & 8191;
            float nz = noise[(size_t)row * NN + j];
            float m = guard(0.01f * nz);
            float adj = sVal[i] - m;
            if (j == row) adj += 1.0f;
            out[(size_t)row * NN + j] = adj;
        }
    }
}

extern "C" void kernel_launch(void* const* d_in, const int* in_sizes, int n_in,
                              void* d_out, int out_size, void* d_ws, size_t ws_size,
                              hipStream_t stream) {
    (void)in_sizes; (void)n_in; (void)out_size; (void)d_ws; (void)ws_size;
    const int*   idx   = (const int*)d_in[0];
    const float* emb1  = (const float*)d_in[1];
    const float* emb2  = (const float*)d_in[2];
    const float* w1    = (const float*)d_in[3];
    const float* b1    = (const float*)d_in[4];
    const float* w2    = (const float*)d_in[5];
    const float* b2    = (const float*)d_in[6];
    const float* noise = (const float*)d_in[7];
    const int*   kptr  = (const int*)d_in[8];

    float* out = (float*)d_out;
    float* Sp      = out;                    // panel (transient)
    float* W32     = out + OFF_W32;
    int*   mrgIdx  = (int*)(out + OFF_MIDX); // persistent screen list (ranked)
    float* mrgVal  = out + OFF_MVAL;

    k1_nodevec<<<NN / 4, 256, 0, stream>>>(idx, emb1, emb2, w1, b1, w2, b2, W32);
    k_init<<<NN * 64 / 256, 256, 0, stream>>>(mrgVal, mrgIdx);

    dim3 g2(PANEL_W / 128, NN / 128);
    for (int p = 0; p < 2; ++p) {
        int colOff = p * PANEL_W;
        k2_score<<<g2, 256, 0, stream>>>(W32, noise, Sp, colOff);
        k3_screen<<<NN / 4, 256, 0, stream>>>(Sp, mrgVal, mrgIdx, colOff);
    }

    k4a_fill<<<64512, 256, 0, stream>>>(out);                       // rows [0,8064)
    k4b_scatter<<<TAILROW0 / 4, 256, 0, stream>>>(mrgIdx, mrgVal, noise, kptr, out);
    k4c_tail<<<1, 1024, 0, stream>>>(mrgIdx, mrgVal, noise, kptr, out);
}

// Round 15
// 678.511 us; speedup vs baseline: 2.4517x; 1.0136x over previous
//
#include <hip/hip_runtime.h>

#define NN 8192
#define DD 64
#define CC 128       // 2*DD
#define PANEL_W 4096 // f32 score panel: 8192*4096*4B = 128MB inside d_out
#define SA 132       // LDS pad: A k-major row stride (words)
#define SB 68        // LDS pad: B k-major row stride (words)

// ---- d_out scratch layout (f32 element offsets; total 67,108,864 floats) --
#define OFF_W32  33554432u   // 8192*128 f32 nodevecs (rows 4096-4223)
#define OFF_MIDX 66060288u   // 8192*64  i32 ranked top-64 list (rows 8064-8127)
#define OFF_MVAL 66584576u   // 8192*64  f32 list scores        (rows 8128-8191)
#define TAILROW0 8064        // rows >= here written only by k4c (single block)

// Optimization barrier: blocks FMA contraction across it (hipcc default
// -ffp-contract=fast would fuse fl(0.01*nz) into the add -> topk flips).
__device__ __forceinline__ float guard(float v) {
    asm volatile("" : "+v"(v));
    return v;
}

// ---- EXACT replica of XLA EmitFastTanh f32, with_fma = true (VERIFIED) ----
__device__ __forceinline__ float xla_tanhf(float x) {
    float xc = fminf(fmaxf(x, -7.99881172180175781f), 7.99881172180175781f);
    float x2 = xc * xc;
    float p = fmaf(x2, -2.76076847742355e-16f, 2.00018790482477e-13f);
    p = fmaf(x2, p, -8.60467152213735e-11f);
    p = fmaf(x2, p, 5.12229709037114e-08f);
    p = fmaf(x2, p, 1.48572235717979e-05f);
    p = fmaf(x2, p, 6.37261928875436e-04f);
    p = fmaf(x2, p, 4.89352455891786e-03f);
    p = xc * p;
    float q = fmaf(x2, 1.19825839466702e-06f, 1.18534705686654e-04f);
    q = fmaf(x2, q, 2.26843463243900e-03f);
    q = fmaf(x2, q, 4.89352518554385e-03f);
    float r = p / q;
    return (fabsf(x) < 0.0004f) ? x : r;
}

// score = fl(max(tanh(fl(3a)),0) + fl(0.01*nz)), no contraction (VERIFIED)
__device__ __forceinline__ float score_of(float a, float nz) {
    float adj = fmaxf(xla_tanhf(3.0f * a), 0.0f);
    float m = guard(0.01f * nz);
    return adj + m;
}

// ---------------------------------------------------------------- K1 (VERIFIED)
__global__ __launch_bounds__(256) void k1_nodevec(
    const int* __restrict__ idx,
    const float* __restrict__ emb1, const float* __restrict__ emb2,
    const float* __restrict__ w1, const float* __restrict__ b1,
    const float* __restrict__ w2, const float* __restrict__ b2,
    float* __restrict__ W32)
{
    __shared__ float sw1[64 * 65], sw2[64 * 65];
    __shared__ float sb1[64], sb2[64];
    __shared__ float se1[4][64], se2[4][64];
    int t = threadIdx.x;
    for (int i = t; i < 4096; i += 256) {
        int r = i >> 6, c = i & 63;
        sw1[r * 65 + c] = w1[i];
        sw2[r * 65 + c] = w2[i];
    }
    if (t < 64) { sb1[t] = b1[t]; sb2[t] = b2[t]; }
    int nl = t >> 6, d = t & 63;
    int n = blockIdx.x * 4 + nl;
    bool is64 = (idx[1] == 0);            // arange: int32 -> 1, int64 LE -> 0
    int g = (is64 ? idx[2 * n] : idx[n]) & 8191;
    se1[nl][d] = emb1[g * 64 + d];
    se2[nl][d] = emb2[g * 64 + d];
    __syncthreads();
    float z1 = 0.0f, z2 = 0.0f;
#pragma unroll 16
    for (int q = 0; q < 64; ++q) {
        z1 = fmaf(se1[nl][q], sw1[d * 65 + q], z1);
        z2 = fmaf(se2[nl][q], sw2[d * 65 + q], z2);
    }
    z1 = 3.0f * guard(z1 + sb1[d]);
    z2 = 3.0f * guard(z2 + sb2[d]);
    W32[n * CC + d]      = xla_tanhf(z1);
    W32[n * CC + 64 + d] = xla_tanhf(z2);
}

// ---------------------------------------------------------------- K_INIT
__global__ __launch_bounds__(256) void k_init(
    float* __restrict__ listVal, int* __restrict__ listIdx)
{
    int i = blockIdx.x * 256 + threadIdx.x;   // NN*64 entries
    listVal[i] = -1.0f;
    listIdx[i] = -1;
}

// ---------------------------------------------------------------- K2 (RETILED)
// 128x64 tile, 8x4 micro-tile, dual accumulators (64 VGPR -- no spill).
// Per-accumulator k-order identical to verified version: kc 0..3 (acc1 for
// kc<2, acc2 for kc>=2), kk ascending, fmaf chain -> bit-identical scores.
__global__ __launch_bounds__(256) void k2_score(
    const float* __restrict__ Wv, const float* __restrict__ noise,
    float* __restrict__ Sp, int colOff)
{
    __shared__ __align__(16) float sA[32 * SA];   // [kk][r], 128 rows
    __shared__ __align__(16) float sB[32 * SB];   // [kk][r], 64 rows
    int t  = threadIdx.x;
    int row0 = blockIdx.y * 128;
    int col0 = blockIdx.x * 64;
    int ty = t >> 4, tx = t & 15;

    float acc1[8][4], acc2[8][4];
#pragma unroll
    for (int i = 0; i < 8; ++i)
#pragma unroll
        for (int j = 0; j < 4; ++j) { acc1[i][j] = 0.0f; acc2[i][j] = 0.0f; }

    for (int kc = 0; kc < 4; ++kc) {
        int k0 = kc * 32;        // A cols: 0-63 = nv1_i, 64-127 = nv2_i
        int kB = k0 ^ 64;        // B swapped half: nv2_j then nv1_j
#pragma unroll
        for (int p = 0; p < 4; ++p) {           // stage A: 128 rows x 32 k
            int q = p * 256 + t;
            int r = q >> 3, f = q & 7;
            float4 av = *(const float4*)&Wv[(row0 + r) * CC + k0 + f * 4];
            int kk = f * 4;
            sA[(kk + 0) * SA + r] = av.x;
            sA[(kk + 1) * SA + r] = av.y;
            sA[(kk + 2) * SA + r] = av.z;
            sA[(kk + 3) * SA + r] = av.w;
        }
#pragma unroll
        for (int p = 0; p < 2; ++p) {           // stage B: 64 rows x 32 k
            int q = p * 256 + t;
            int r = q >> 3, f = q & 7;
            float4 bv = *(const float4*)&Wv[(colOff + col0 + r) * CC + kB + f * 4];
            int kk = f * 4;
            sB[(kk + 0) * SB + r] = bv.x;
            sB[(kk + 1) * SB + r] = bv.y;
            sB[(kk + 2) * SB + r] = bv.z;
            sB[(kk + 3) * SB + r] = bv.w;
        }
        __syncthreads();
        bool first = (kc < 2);
#pragma unroll 8
        for (int kk = 0; kk < 32; ++kk) {
            float4 a0 = *(const float4*)&sA[kk * SA + ty * 8];
            float4 a1 = *(const float4*)&sA[kk * SA + ty * 8 + 4];
            float4 b0 = *(const float4*)&sB[kk * SB + tx * 4];
            float a[8] = {a0.x, a0.y, a0.z, a0.w, a1.x, a1.y, a1.z, a1.w};
            float b[4] = {b0.x, b0.y, b0.z, b0.w};
            if (first) {
#pragma unroll
                for (int i = 0; i < 8; ++i)
#pragma unroll
                    for (int j = 0; j < 4; ++j)
                        acc1[i][j] = fmaf(a[i], b[j], acc1[i][j]);
            } else {
#pragma unroll
                for (int i = 0; i < 8; ++i)
#pragma unroll
                    for (int j = 0; j < 4; ++j)
                        acc2[i][j] = fmaf(a[i], b[j], acc2[i][j]);
            }
        }
        __syncthreads();
    }
#pragma unroll
    for (int i = 0; i < 8; ++i) {
        int gr = row0 + ty * 8 + i;
        int gc = col0 + tx * 4;
        float4 nz = *(const float4*)&noise[(size_t)gr * NN + colOff + gc];
        float4 o;
        o.x = score_of(guard(acc1[i][0] - acc2[i][0]), nz.x);
        o.y = score_of(guard(acc1[i][1] - acc2[i][1]), nz.y);
        o.z = score_of(guard(acc1[i][2] - acc2[i][2]), nz.z);
        o.w = score_of(guard(acc1[i][3] - acc2[i][3]), nz.w);
        *(float4*)&Sp[(size_t)gr * PANEL_W + gc] = o;
    }
}

// ---------------------------------------------------------------- K3 (VERIFIED)
// One wave per row: persistent sorted top-64 register list, ballot-batched
// insertion; ascending-j + '>' filter + 'Lv >= v stays ahead' = stable topk.
__global__ __launch_bounds__(256) void k3_screen(
    const float* __restrict__ Sp,
    float* __restrict__ listVal, int* __restrict__ listIdx, int colOff)
{
    int lane = threadIdx.x & 63;
    int w    = threadIdx.x >> 6;
    int row  = blockIdx.x * 4 + w;
    const float* Srow = Sp + (size_t)row * PANEL_W;

    float Lv = listVal[row * 64 + lane];
    int   Lj = listIdx[row * 64 + lane];

    for (int c0 = 0; c0 < PANEL_W; c0 += 256) {
        float s0 = Srow[c0 + lane];
        float s1 = Srow[c0 + 64 + lane];
        float s2 = Srow[c0 + 128 + lane];
        float s3 = Srow[c0 + 192 + lane];
#pragma unroll
        for (int u = 0; u < 4; ++u) {
            float s = (u == 0) ? s0 : (u == 1) ? s1 : (u == 2) ? s2 : s3;
            int jb = colOff + c0 + u * 64;
            float tau = __shfl(Lv, 63);
            unsigned long long m = __ballot(s > tau);
            while (m) {
                int b = __ffsll((unsigned long long)m) - 1;
                m &= m - 1;
                float v = __shfl(s, b);
                tau = __shfl(Lv, 63);            // refresh (list grew)
                if (v > tau) {
                    float Lu = __shfl_up(Lv, 1);
                    int   Ju = __shfl_up(Lj, 1);
                    bool ge  = (Lv >= v);                 // ties: earlier j stays
                    bool geu = (lane == 0) || (Lu >= v);
                    float nv = ge ? Lv : (geu ? v : Lu);
                    int   nj = ge ? Lj : (geu ? (jb + b) : Ju);
                    Lv = nv; Lj = nj;
                }
            }
        }
    }
    listVal[row * 64 + lane] = Lv;
    listIdx[row * 64 + lane] = Lj;
}

// ---------------------------------------------------------------- K4a (VERIFIED)
__global__ __launch_bounds__(256) void k4a_fill(float* __restrict__ out)
{
    int i4 = blockIdx.x * 256 + threadIdx.x;   // float4 index < 16,515,072
    int f0 = i4 * 4;
    int row = f0 >> 13;
    int colbase = f0 & 8191;
    int drel = row - colbase;
    float4 z = make_float4(0.f, 0.f, 0.f, 0.f);
    if (drel >= 0 && drel < 4) ((float*)&z)[drel] = 1.0f;
    *(float4*)&out[f0] = z;
}

// ---------------------------------------------------------------- K4b (VERIFIED)
__global__ __launch_bounds__(256) void k4b_scatter(
    const int* __restrict__ mrgIdx, const float* __restrict__ mrgVal,
    const float* __restrict__ noise, const int* __restrict__ kptr,
    float* __restrict__ out)
{
    int lane = threadIdx.x & 63;
    int w    = threadIdx.x >> 6;
    int row  = blockIdx.x * 4 + w;
    int kk = kptr[0]; if (kk > 64) kk = 64; if (kk < 1) kk = 1;
    if (lane < kk) {
        int   j = mrgIdx[row * 64 + lane] & 8191;
        float s = mrgVal[row * 64 + lane];
        float nz = noise[(size_t)row * NN + j];
        float m = guard(0.01f * nz);
        float adj = s - m;
        if (j == row) adj += 1.0f;
        out[(size_t)row * NN + j] = adj;
    }
}

// ---------------------------------------------------------------- K4c (VERIFIED)
__global__ __launch_bounds__(1024) void k4c_tail(
    const int* __restrict__ mrgIdx, const float* __restrict__ mrgVal,
    const float* __restrict__ noise, const int* __restrict__ kptr,
    float* __restrict__ out)
{
    __shared__ int   sIdx[128 * 64];
    __shared__ float sVal[128 * 64];
    int t = threadIdx.x;
    int kk = kptr[0]; if (kk > 64) kk = 64; if (kk < 1) kk = 1;

    for (int i = t; i < 128 * 64; i += 1024) {
        sIdx[i] = mrgIdx[(TAILROW0 + (i >> 6)) * 64 + (i & 63)];
        sVal[i] = mrgVal[(TAILROW0 + (i >> 6)) * 64 + (i & 63)];
    }
    __syncthreads();

    const int base = TAILROW0 * NN;           // 66,060,288 fits int
    for (int q = t; q < 262144; q += 1024) {  // float4 count for 128 rows
        int f0 = base + q * 4;
        int row = f0 >> 13;
        int colbase = f0 & 8191;
        int drel = row - colbase;
        float4 z = make_float4(0.f, 0.f, 0.f, 0.f);
        if (drel >= 0 && drel < 4) ((float*)&z)[drel] = 1.0f;
        *(float4*)&out[f0] = z;
    }
    __syncthreads();

    for (int i = t; i < 128 * 64; i += 1024) {
        int s = i & 63;
        if (s < kk) {
            int row = TAILROW0 + (i >> 6);
            int j = sIdx[i] & 8191;
            float nz = noise[(size_t)row * NN + j];
            float m = guard(0.01f * nz);
            float adj = sVal[i] - m;
            if (j == row) adj += 1.0f;
            out[(size_t)row * NN + j] = adj;
        }
    }
}

extern "C" void kernel_launch(void* const* d_in, const int* in_sizes, int n_in,
                              void* d_out, int out_size, void* d_ws, size_t ws_size,
                              hipStream_t stream) {
    (void)in_sizes; (void)n_in; (void)out_size; (void)d_ws; (void)ws_size;
    const int*   idx   = (const int*)d_in[0];
    const float* emb1  = (const float*)d_in[1];
    const float* emb2  = (const float*)d_in[2];
    const float* w1    = (const float*)d_in[3];
    const float* b1    = (const float*)d_in[4];
    const float* w2    = (const float*)d_in[5];
    const float* b2    = (const float*)d_in[6];
    const float* noise = (const float*)d_in[7];
    const int*   kptr  = (const int*)d_in[8];

    float* out = (float*)d_out;
    float* Sp      = out;                    // panel (transient)
    float* W32     = out + OFF_W32;
    int*   mrgIdx  = (int*)(out + OFF_MIDX); // persistent screen list (ranked)
    float* mrgVal  = out + OFF_MVAL;

    k1_nodevec<<<NN / 4, 256, 0, stream>>>(idx, emb1, emb2, w1, b1, w2, b2, W32);
    k_init<<<NN * 64 / 256, 256, 0, stream>>>(mrgVal, mrgIdx);

    dim3 g2(PANEL_W / 64, NN / 128);         // 64 x 64 = 4096 blocks per panel
    for (int p = 0; p < 2; ++p) {
        int colOff = p * PANEL_W;
        k2_score<<<g2, 256, 0, stream>>>(W32, noise, Sp, colOff);
        k3_screen<<<NN / 4, 256, 0, stream>>>(Sp, mrgVal, mrgIdx, colOff);
    }

    k4a_fill<<<64512, 256, 0, stream>>>(out);                       // rows [0,8064)
    k4b_scatter<<<TAILROW0 / 4, 256, 0, stream>>>(mrgIdx, mrgVal, noise, kptr, out);
    k4c_tail<<<1, 1024, 0, stream>>>(mrgIdx, mrgVal, noise, kptr, out);
}